// Round 12
// baseline (45.838 us; speedup 1.0000x reference)
//
#include <hip/hip_runtime.h>

typedef float    f32x4  __attribute__((ext_vector_type(4)));
typedef float    f32x16 __attribute__((ext_vector_type(16)));
typedef _Float16 half8  __attribute__((ext_vector_type(8)));

constexpr int NB = 8;
constexpr int NQ = 2048;
constexpr int NKEY = 2048;
constexpr int DD = 64;
constexpr int KB = 32;   // keys per wave-iteration (one 32-key chunk)

// scores kept in log2 domain: fold log2(e) into the 1/sqrt(d) scale
#define QSCALE (0.125f * 1.44269504088896340736f)

__device__ inline unsigned pkh(float a, float b) {
    return __builtin_bit_cast(unsigned, __builtin_amdgcn_cvt_pkrtz(a, b));
}

// P (f32 C-layout regs) -> f16 A-fragments (verified R5/R6), PV from V^T LDS.
// V^T LDS: 64 d-rows x 64B; byte(d,key) = d*64 + ((key*2) ^ ((d&3)<<4)).
__device__ __forceinline__ void pv_chunk(
    const f32x16& sv, const char* __restrict__ vsm,
    int hi, int ql, int swzq, f32x16& o0, f32x16& o1)
{
    const unsigned w0 = pkh(sv[0],  sv[1]),  w1 = pkh(sv[2],  sv[3]);
    const unsigned w2 = pkh(sv[4],  sv[5]),  w3 = pkh(sv[6],  sv[7]);
    const unsigned w4 = pkh(sv[8],  sv[9]),  w5 = pkh(sv[10], sv[11]);
    const unsigned w6 = pkh(sv[12], sv[13]), w7 = pkh(sv[14], sv[15]);
    const unsigned p0 = __shfl_xor(w0, 32), p1 = __shfl_xor(w1, 32);
    const unsigned p2 = __shfl_xor(w2, 32), p3 = __shfl_xor(w3, 32);
    const unsigned p4 = __shfl_xor(w4, 32), p5 = __shfl_xor(w5, 32);
    const unsigned p6 = __shfl_xor(w6, 32), p7 = __shfl_xor(w7, 32);
    const bool h1 = (hi != 0);
    union { unsigned u[4]; half8 h; } A0, A1;
    A0.u[0] = h1 ? p2 : w0;  A0.u[1] = h1 ? p3 : w1;
    A0.u[2] = h1 ? w2 : p0;  A0.u[3] = h1 ? w3 : p1;
    A1.u[0] = h1 ? p6 : w4;  A1.u[1] = h1 ? p7 : w5;
    A1.u[2] = h1 ? w6 : p4;  A1.u[3] = h1 ? w7 : p5;

    __builtin_amdgcn_s_setprio(1);
#pragma unroll
    for (int t = 0; t < 2; ++t) {
        const int co = t * 32 + hi * 16;          // key-byte offset in row
        const half8 vb0 = *(const half8*)(vsm + ql * 64        + (co ^ swzq));
        const half8 vb1 = *(const half8*)(vsm + (32 + ql) * 64 + (co ^ swzq));
        const half8 pa = (t == 0) ? A0.h : A1.h;
        o0 = __builtin_amdgcn_mfma_f32_32x32x16_f16(pa, vb0, o0, 0, 0, 0);
        o1 = __builtin_amdgcn_mfma_f32_32x32x16_f16(pa, vb1, o1, 0, 0, 0);
    }
    __builtin_amdgcn_s_setprio(0);
}

// Fused flash attention: 1 block = 8 waves on one 32-q-row tile, 8-way split-K,
// per-wave-private LDS staging (no main-loop barriers), 8-way LDS merge at end.
// LDS 67.6KB/block -> 2 blocks/CU = 16 waves/CU = 4 waves/SIMD (2x R9).
__global__ __launch_bounds__(512, 4) void attn_fused(
    const float* __restrict__ Qp, const float* __restrict__ Kp,
    const float* __restrict__ Vp, const int* __restrict__ VL,
    float* __restrict__ Op)
{
    // 8 x (K 4KB + V^T 4KB) staging; Obuf overlays staging; Mb/Lb beyond
    __shared__ __align__(16) char pool[67584];

    const int tid  = threadIdx.x;
    const int wv   = tid >> 6;          // 0..7
    const int lane = tid & 63;
    const int ql   = lane & 31;
    const int hi   = lane >> 5;

    char* Ksm = pool + wv * 8192;
    char* Vsm = Ksm + 4096;

    // bijective mapping; co-resident pair (g, g+256) gets DIFFERENT batches
    const int g  = blockIdx.x;
    const int b  = ((g >> 3) & 7) ^ ((g >> 8) << 2);
    const int qt = (g & 7) | (((g >> 6) & 7) << 3);
    const int qbase = qt * 32;

    const int vlen = VL[b];
    const int numt = (vlen + KB - 1) / KB;

    // ---- Q B-fragments: lane holds Q[qbase+ql][d = c*16 + hi*8 + j] ----
    const float* qsrc = Qp + ((size_t)b * NQ + qbase + ql) * DD;
    half8 qf[4];
#pragma unroll
    for (int c = 0; c < 4; ++c) {
        f32x4 f0 = *(const f32x4*)(qsrc + c * 16 + hi * 8);
        f32x4 f1 = *(const f32x4*)(qsrc + c * 16 + hi * 8 + 4);
        half8 h;
#pragma unroll
        for (int j = 0; j < 4; ++j) {
            h[j]     = (_Float16)(f0[j] * QSCALE);
            h[4 + j] = (_Float16)(f1[j] * QSCALE);
        }
        qf[c] = h;
    }

    f32x16 o0 = {}, o1 = {};
    float mrun = -1e30f, lrun = 0.f;

    // staging lane roles (all coalesced)
    const int kr_ = lane >> 3;          // K: row-in-8
    const int kd0 = (lane & 7) * 8;     // K: d0 (32B per lane)
    const int vk2 = (lane >> 4) * 2;    // V: key-pair base
    const int vd0 = (lane & 15) * 4;    // V: d0 (16B per lane)
    const int swzq = (ql & 3) << 4;     // V^T swizzle, == for ql and 32+ql

    // ---- main loop: wave wv owns key tiles wv, wv+8, ... (no barriers) ----
    for (int t = wv; t < numt; t += 8) {
        const int kbase = t * KB;
        const float* kbp = Kp + ((size_t)b * NKEY + kbase) * DD;
        const float* vbp = Vp + ((size_t)b * NKEY + kbase) * DD;

        // K tile loads (32 rows) then K->LDS; staged before V loads to cap
        // register liveness (R10 spill lesson)
        f32x4 ka[4][2];
#pragma unroll
        for (int i = 0; i < 4; ++i) {
            const float* src = kbp + (size_t)(i * 8 + kr_) * DD + kd0;
            ka[i][0] = *(const f32x4*)src;
            ka[i][1] = *(const f32x4*)(src + 4);
        }
#pragma unroll
        for (int i = 0; i < 4; ++i) {
            half8 h;
#pragma unroll
            for (int j = 0; j < 4; ++j) {
                h[j]     = (_Float16)ka[i][0][j];
                h[4 + j] = (_Float16)ka[i][1][j];
            }
            const int off = ((i * 8 + kr_) * 128 + kd0 * 2) ^ (kr_ << 4);
            *(half8*)(Ksm + off) = h;
        }

        // V tile loads issued now; latency hides under QK^T
        f32x4 va[4][2];
#pragma unroll
        for (int i = 0; i < 4; ++i) {
            const float* src = vbp + (size_t)(i * 8 + vk2) * DD + vd0;
            va[i][0] = *(const f32x4*)src;
            va[i][1] = *(const f32x4*)(src + DD);
        }

        // ---- swapped QK^T (K from LDS; R6-verified layout) ----
        f32x16 sv = {};
        __builtin_amdgcn_s_setprio(1);
#pragma unroll
        for (int c = 0; c < 4; ++c) {
            const half8 kf = *(const half8*)(Ksm +
                ((ql * 128 + c * 32 + hi * 16) ^ ((ql & 7) << 4)));
            sv = __builtin_amdgcn_mfma_f32_32x32x16_f16(kf, qf[c], sv, 0, 0, 0);
        }
        __builtin_amdgcn_s_setprio(0);

        // V -> LDS transposed (key-pair packed b32 writes, swizzled)
#pragma unroll
        for (int i = 0; i < 4; ++i) {
#pragma unroll
            for (int jj = 0; jj < 4; ++jj) {
                const int d = vd0 + jj;
                const int k = i * 4 + (lane >> 4);   // key-pair index
                const unsigned w = pkh(va[i][0][jj], va[i][1][jj]);
                *(unsigned*)(Vsm + d * 64 + ((k * 4) ^ ((d & 3) << 4))) = w;
            }
        }

        // ---- mask (boundary tile only; wave-uniform branch) ----
        if (kbase + KB > vlen) {
#pragma unroll
            for (int r = 0; r < 16; ++r) {
                const int krow = (r & 3) + 8 * (r >> 2) + 4 * hi;
                sv[r] = (kbase + krow < vlen) ? sv[r] : -1e30f;
            }
        }

        // ---- online softmax in log2 domain (lane state is q = ql) ----
        float mx[16];
#pragma unroll
        for (int r = 0; r < 16; ++r) mx[r] = sv[r];
#pragma unroll
        for (int st = 8; st > 0; st >>= 1)
#pragma unroll
            for (int r = 0; r < st; ++r) mx[r] = fmaxf(mx[r], mx[r + st]);
        float mr = fmaxf(mx[0], __shfl_xor(mx[0], 32));

        if (!__all(mr <= mrun + 8.f)) {     // defer-max (T13)
            const float mn = fmaxf(mrun, mr);
            const float alpha = __builtin_amdgcn_exp2f(mrun - mn);
            lrun *= alpha;
            mrun = mn;
#pragma unroll
            for (int r = 0; r < 16; ++r) {
                const int qr = (r & 3) + 8 * (r >> 2) + 4 * hi;
                const float ar = __shfl(alpha, qr);
                o0[r] *= ar;
                o1[r] *= ar;
            }
        }

#pragma unroll
        for (int r = 0; r < 16; ++r)
            sv[r] = __builtin_amdgcn_exp2f(sv[r] - mrun);
        float sx[16];
#pragma unroll
        for (int r = 0; r < 16; ++r) sx[r] = sv[r];
#pragma unroll
        for (int st = 8; st > 0; st >>= 1)
#pragma unroll
            for (int r = 0; r < st; ++r) sx[r] += sx[r + st];
        lrun += sx[0] + __shfl_xor(sx[0], 32);

        // ---- PV (V^T from LDS) ----
        pv_chunk(sv, Vsm, hi, ql, swzq, o0, o1);
    }

    // ---- 8-way cross-wave merge (Obuf overlays staging after barrier) ----
    __syncthreads();
    float* Mb = (float*)(pool + 65536);
    float* Lb = (float*)(pool + 65536 + 1024);
    float (*Obuf)[32][64] = (float (*)[32][64])pool;

    if (hi == 0) { Mb[wv * 32 + ql] = mrun; Lb[wv * 32 + ql] = lrun; }
    __syncthreads();

    float Mtot = -1e30f;
#pragma unroll
    for (int w = 0; w < 8; ++w)
        if (Lb[w * 32 + ql] > 0.f) Mtot = fmaxf(Mtot, Mb[w * 32 + ql]);
    const float wown = (lrun > 0.f) ? __builtin_amdgcn_exp2f(mrun - Mtot) : 0.f;

#pragma unroll
    for (int r = 0; r < 16; ++r) {
        const int qr = (r & 3) + 8 * (r >> 2) + 4 * hi;
        const float wr = __shfl(wown, qr);
        Obuf[wv][qr][ql]      = o0[r] * wr;
        Obuf[wv][qr][ql + 32] = o1[r] * wr;
    }
    __syncthreads();

    // readback: thread handles q = tid>>4, d = (tid&15)*4 .. +3 (coalesced)
    {
        const int q  = tid >> 4;
        const int d0 = (tid & 15) * 4;
        float Mq = -1e30f;
#pragma unroll
        for (int w = 0; w < 8; ++w)
            if (Lb[w * 32 + q] > 0.f) Mq = fmaxf(Mq, Mb[w * 32 + q]);
        float Ltot = 0.f;
#pragma unroll
        for (int w = 0; w < 8; ++w) {
            const float lw = Lb[w * 32 + q];
            if (lw > 0.f) Ltot += lw * __builtin_amdgcn_exp2f(Mb[w * 32 + q] - Mq);
        }
        f32x4 acc = {};
#pragma unroll
        for (int w = 0; w < 8; ++w)
            acc += *(const f32x4*)(&Obuf[w][q][d0]);
        const float inv = 1.0f / Ltot;
        f32x4 outv;
#pragma unroll
        for (int j = 0; j < 4; ++j) outv[j] = acc[j] * inv;
        *(f32x4*)(Op + ((size_t)b * NQ + qbase + q) * DD + d0) = outv;
    }
}

extern "C" void kernel_launch(void* const* d_in, const int* in_sizes, int n_in,
                              void* d_out, int out_size, void* d_ws, size_t ws_size,
                              hipStream_t stream) {
    const float* Qp = (const float*)d_in[0];
    const float* Kp = (const float*)d_in[1];
    const float* Vp = (const float*)d_in[2];
    const int*   VL = (const int*)d_in[3];
    float* Op = (float*)d_out;

    dim3 block(512);
    dim3 grid(NB * (NQ / 32));   // 512 blocks = 2/CU at 8 waves each
    hipLaunchKernelGGL(attn_fused, grid, block, 0, stream, Qp, Kp, Vp, VL, Op);
}

// Round 13
// 30.806 us; speedup vs baseline: 1.4879x; 1.4879x over previous
//
#include <hip/hip_runtime.h>

typedef float    f32x4  __attribute__((ext_vector_type(4)));
typedef float    f32x16 __attribute__((ext_vector_type(16)));
typedef _Float16 half8  __attribute__((ext_vector_type(8)));

constexpr int NB = 8;
constexpr int NQ = 2048;
constexpr int NKEY = 2048;
constexpr int DD = 64;
constexpr int KB = 64;            // keys per wave-iteration
constexpr int NT = NKEY / KB;     // 32 tiles per batch
constexpr size_t TILE_BYTES = (size_t)KB * DD * 2;   // 8 KB f16 tile

// scores kept in log2 domain: fold log2(e) into the 1/sqrt(d) scale
#define QSCALE (0.125f * 1.44269504088896340736f)

__device__ inline unsigned pkh(float a, float b) {
    return __builtin_bit_cast(unsigned, __builtin_amdgcn_cvt_pkrtz(a, b));
}
// V^T swizzle (R9-verified): byte(d,key) = d*128 + ((key*2) ^ vswz(d))
__device__ inline int vswz(int d) {
    return (((d >> 3) & 3) | ((d & 1) << 2)) << 4;
}

#define GLL(gp, lp) __builtin_amdgcn_global_load_lds( \
    (const __attribute__((address_space(1))) void*)(gp), \
    (__attribute__((address_space(3))) void*)(lp), 16, 0, 0)

// ---------- pre-pass: K,V fp32 -> f16 tiles, PRE-SWIZZLED to LDS layouts ----------
// blocks [0,256): K tiles; [256,512): V tiles (transposed via LDS).
__global__ __launch_bounds__(256) void convert_kv(
    const float* __restrict__ Kp, const float* __restrict__ Vp,
    char* __restrict__ Kh, char* __restrict__ Vt)
{
    __shared__ __align__(16) char vbuf[64 * 144];
    const int g    = blockIdx.x;
    const bool isV = (g >= NB * NT);
    const int bt   = isV ? g - NB * NT : g;
    const int tid  = threadIdx.x;
    const int k    = tid >> 2;        // key row 0..63
    const int c    = tid & 3;         // 16-elem d chunk

    const int b = bt >> 5, T = bt & 31;
    const float* src = (isV ? Vp : Kp) + ((size_t)b * NKEY + T * 64 + k) * DD + c * 16;
    half8 lo, hi;
#pragma unroll
    for (int j = 0; j < 2; ++j) {
        f32x4 f0 = *(const f32x4*)(src + j * 8);
        f32x4 f1 = *(const f32x4*)(src + j * 8 + 4);
#pragma unroll
        for (int i = 0; i < 4; ++i) {
            if (j == 0) { lo[i] = (_Float16)f0[i]; lo[4 + i] = (_Float16)f1[i]; }
            else        { hi[i] = (_Float16)f0[i]; hi[4 + i] = (_Float16)f1[i]; }
        }
    }

    if (!isV) {
        // K layout: byte(key,d) = (key*128 + d*2) ^ ((key&7)<<4)
        char* dst = Kh + (size_t)bt * TILE_BYTES;
        const int base = k * 128 + c * 32;
        const int swz  = (k & 7) << 4;
        *(half8*)(dst + (base ^ swz))        = lo;
        *(half8*)(dst + ((base + 16) ^ swz)) = hi;
    } else {
        // stage rows in LDS (144B stride vs bank conflicts), then transpose
        *(half8*)(vbuf + k * 144 + c * 32)      = lo;
        *(half8*)(vbuf + k * 144 + c * 32 + 16) = hi;
        __syncthreads();
        const int d  = tid >> 2;      // d row 0..63
        const int c2 = tid & 3;       // 16-key chunk
        half8 l2, h2;
#pragma unroll
        for (int j = 0; j < 8; ++j) {
            l2[j] = *(const _Float16*)(vbuf + (c2 * 16 + j) * 144 + d * 2);
            h2[j] = *(const _Float16*)(vbuf + (c2 * 16 + 8 + j) * 144 + d * 2);
        }
        char* dst = Vt + (size_t)bt * TILE_BYTES;
        const int base = d * 128 + c2 * 32;
        const int swz  = vswz(d);
        *(half8*)(dst + (base ^ swz))        = l2;
        *(half8*)(dst + ((base + 16) ^ swz)) = h2;
    }
}

// P (f32 C-layout regs) -> f16 A-fragments (verified R5/R6), PV from swizzled V^T LDS.
__device__ __forceinline__ void pv_chunk(
    const f32x16& sv, const char* __restrict__ vsm, int koff,
    int hi, int ql, int swzq, f32x16& o0, f32x16& o1)
{
    const unsigned w0 = pkh(sv[0],  sv[1]),  w1 = pkh(sv[2],  sv[3]);
    const unsigned w2 = pkh(sv[4],  sv[5]),  w3 = pkh(sv[6],  sv[7]);
    const unsigned w4 = pkh(sv[8],  sv[9]),  w5 = pkh(sv[10], sv[11]);
    const unsigned w6 = pkh(sv[12], sv[13]), w7 = pkh(sv[14], sv[15]);
    const unsigned p0 = __shfl_xor(w0, 32), p1 = __shfl_xor(w1, 32);
    const unsigned p2 = __shfl_xor(w2, 32), p3 = __shfl_xor(w3, 32);
    const unsigned p4 = __shfl_xor(w4, 32), p5 = __shfl_xor(w5, 32);
    const unsigned p6 = __shfl_xor(w6, 32), p7 = __shfl_xor(w7, 32);
    const bool h1 = (hi != 0);
    union { unsigned u[4]; half8 h; } A0, A1;
    A0.u[0] = h1 ? p2 : w0;  A0.u[1] = h1 ? p3 : w1;
    A0.u[2] = h1 ? w2 : p0;  A0.u[3] = h1 ? w3 : p1;
    A1.u[0] = h1 ? p6 : w4;  A1.u[1] = h1 ? p7 : w5;
    A1.u[2] = h1 ? w6 : p4;  A1.u[3] = h1 ? w7 : p5;

    __builtin_amdgcn_s_setprio(1);
#pragma unroll
    for (int t = 0; t < 2; ++t) {
        const int co = koff + t * 32 + hi * 16;       // key-byte offset in row
        const half8 vb0 = *(const half8*)(vsm + ql * 128        + (co ^ swzq));
        const half8 vb1 = *(const half8*)(vsm + (32 + ql) * 128 + (co ^ swzq));
        const half8 pa = (t == 0) ? A0.h : A1.h;
        o0 = __builtin_amdgcn_mfma_f32_32x32x16_f16(pa, vb0, o0, 0, 0, 0);
        o1 = __builtin_amdgcn_mfma_f32_32x32x16_f16(pa, vb1, o1, 0, 0, 0);
    }
    __builtin_amdgcn_s_setprio(0);
}

// Fused flash attention: 1 block = 4 waves on one 32-q-row tile, split-K across
// waves, per-wave-private LDS staging via global_load_lds (no main-loop barriers),
// LDS merge at end.
__global__ __launch_bounds__(256, 2) void attn_fused(
    const float* __restrict__ Qp, const char* __restrict__ Kh,
    const char* __restrict__ Vt, const int* __restrict__ VL,
    float* __restrict__ Op)
{
    // 4 x (K 8KB + V^T 8KB) staging; merge buffers overlaid after barrier
    __shared__ __align__(16) char pool[65536];

    const int tid  = threadIdx.x;
    const int wv   = tid >> 6;
    const int lane = tid & 63;
    const int ql   = lane & 31;
    const int hi   = lane >> 5;

    char* Ksm = pool + wv * 16384;
    char* Vsm = Ksm + 8192;

    // balanced bijective mapping: per-XCD (g%8) all batches appear; co-resident
    // pair (g, g+256) gets batches b and b^4 (f16 K+V fits every L2 anyway)
    const int g  = blockIdx.x;
    const int m  = g >> 3;
    const int b  = (m ^ (m >> 3)) & 7;
    const int qt = (g & 7) | ((m >> 3) << 3);
    const int qbase = qt * 32;

    const int vlen = VL[b];
    const int numt = (vlen + KB - 1) / KB;

    // ---- Q B-fragments: lane holds Q[qbase+ql][d = c*16 + hi*8 + j] ----
    const float* qsrc = Qp + ((size_t)b * NQ + qbase + ql) * DD;
    half8 qf[4];
#pragma unroll
    for (int c = 0; c < 4; ++c) {
        f32x4 f0 = *(const f32x4*)(qsrc + c * 16 + hi * 8);
        f32x4 f1 = *(const f32x4*)(qsrc + c * 16 + hi * 8 + 4);
        half8 h;
#pragma unroll
        for (int j = 0; j < 4; ++j) {
            h[j]     = (_Float16)(f0[j] * QSCALE);
            h[4 + j] = (_Float16)(f1[j] * QSCALE);
        }
        qf[c] = h;
    }

    f32x16 o0 = {}, o1 = {};
    float mrun = -1e30f, lrun = 0.f;
    const int swzq = vswz(ql);          // == vswz(32+ql)

    // ---- main loop: wave wv owns key tiles wv, wv+4, ... (no barriers) ----
    for (int t = wv; t < numt; t += 4) {
        const int kbase = t * KB;
        const char* ksrc = Kh + (size_t)(b * NT + t) * TILE_BYTES + lane * 16;
        const char* vsrc = Vt + (size_t)(b * NT + t) * TILE_BYTES + lane * 16;

        // stage K then V via direct-to-LDS DMA (linear dest; source pre-swizzled)
        __builtin_amdgcn_sched_barrier(0);
#pragma unroll
        for (int j = 0; j < 8; ++j) GLL(ksrc + j * 1024, Ksm + j * 1024);
#pragma unroll
        for (int j = 0; j < 8; ++j) GLL(vsrc + j * 1024, Vsm + j * 1024);
        asm volatile("s_waitcnt vmcnt(8)" ::: "memory");   // K landed; V in flight
        __builtin_amdgcn_sched_barrier(0);

        // ---- swapped QK^T, two 32-key chunks (K from LDS; R6-verified) ----
        f32x16 svA = {}, svB = {};
        __builtin_amdgcn_s_setprio(1);
#pragma unroll
        for (int c = 0; c < 4; ++c) {
            const half8 kfA = *(const half8*)(Ksm +
                ((ql * 128 + c * 32 + hi * 16) ^ ((ql & 7) << 4)));
            svA = __builtin_amdgcn_mfma_f32_32x32x16_f16(kfA, qf[c], svA, 0, 0, 0);
            const half8 kfB = *(const half8*)(Ksm +
                (((32 + ql) * 128 + c * 32 + hi * 16) ^ ((ql & 7) << 4)));
            svB = __builtin_amdgcn_mfma_f32_32x32x16_f16(kfB, qf[c], svB, 0, 0, 0);
        }
        __builtin_amdgcn_s_setprio(0);

        // ---- mask (boundary tile only; wave-uniform branch) ----
        if (kbase + KB > vlen) {
#pragma unroll
            for (int r = 0; r < 16; ++r) {
                const int krow = (r & 3) + 8 * (r >> 2) + 4 * hi;
                svA[r] = (kbase + krow < vlen)      ? svA[r] : -1e30f;
                svB[r] = (kbase + 32 + krow < vlen) ? svB[r] : -1e30f;
            }
        }

        // ---- online softmax in log2 domain (lane state is q = ql) ----
        float mx[16];
#pragma unroll
        for (int r = 0; r < 16; ++r) mx[r] = fmaxf(svA[r], svB[r]);
#pragma unroll
        for (int st = 8; st > 0; st >>= 1)
#pragma unroll
            for (int r = 0; r < st; ++r) mx[r] = fmaxf(mx[r], mx[r + st]);
        float mr = fmaxf(mx[0], __shfl_xor(mx[0], 32));

        if (!__all(mr <= mrun + 8.f)) {     // defer-max (T13)
            const float mn = fmaxf(mrun, mr);
            const float alpha = __builtin_amdgcn_exp2f(mrun - mn);
            lrun *= alpha;
            mrun = mn;
#pragma unroll
            for (int r = 0; r < 16; ++r) {
                const int qr = (r & 3) + 8 * (r >> 2) + 4 * hi;
                const float ar = __shfl(alpha, qr);
                o0[r] *= ar;
                o1[r] *= ar;
            }
        }

#pragma unroll
        for (int r = 0; r < 16; ++r) {
            svA[r] = __builtin_amdgcn_exp2f(svA[r] - mrun);
            svB[r] = __builtin_amdgcn_exp2f(svB[r] - mrun);
        }
        float sx[16];
#pragma unroll
        for (int r = 0; r < 16; ++r) sx[r] = svA[r] + svB[r];
#pragma unroll
        for (int st = 8; st > 0; st >>= 1)
#pragma unroll
            for (int r = 0; r < st; ++r) sx[r] += sx[r + st];
        lrun += sx[0] + __shfl_xor(sx[0], 32);

        // ---- PV (V landed by now; enforce then read) ----
        asm volatile("s_waitcnt vmcnt(0)" ::: "memory");
        __builtin_amdgcn_sched_barrier(0);
        pv_chunk(svA, Vsm, 0,  hi, ql, swzq, o0, o1);
        pv_chunk(svB, Vsm, 64, hi, ql, swzq, o0, o1);
    }

    // ---- cross-wave merge (LDS overlaid on staging after barrier) ----
    __syncthreads();
    float* Mb = (float*)(pool + 32768);
    float* Lb = (float*)(pool + 32768 + 512);
    float* Tb = (float*)(pool + 32768 + 1024);
    float (*Obuf)[32][64] = (float (*)[32][64])pool;

    if (hi == 0) { Mb[wv * 32 + ql] = mrun; Lb[wv * 32 + ql] = lrun; }
    __syncthreads();

    float Mtot = -1e30f;
#pragma unroll
    for (int w = 0; w < 4; ++w)
        if (Lb[w * 32 + ql] > 0.f) Mtot = fmaxf(Mtot, Mb[w * 32 + ql]);
    float Ltot = 0.f;
#pragma unroll
    for (int w = 0; w < 4; ++w) {
        const float lw = Lb[w * 32 + ql];
        if (lw > 0.f) Ltot += lw * __builtin_amdgcn_exp2f(Mb[w * 32 + ql] - Mtot);
    }
    const float wown = (lrun > 0.f) ? __builtin_amdgcn_exp2f(mrun - Mtot) : 0.f;
    if (wv == 0 && hi == 0) Tb[ql] = Ltot;

#pragma unroll
    for (int r = 0; r < 16; ++r) {
        const int qr = (r & 3) + 8 * (r >> 2) + 4 * hi;
        const float wr = __shfl(wown, qr);
        Obuf[wv][qr][ql]      = o0[r] * wr;
        Obuf[wv][qr][ql + 32] = o1[r] * wr;
    }
    __syncthreads();

    // readback: wave wv sums q rows wv*8..+7; lane = d (coalesced 256B rows)
#pragma unroll
    for (int k = 0; k < 8; ++k) {
        const int q = wv * 8 + k;
        const float sum = Obuf[0][q][lane] + Obuf[1][q][lane]
                        + Obuf[2][q][lane] + Obuf[3][q][lane];
        Op[((size_t)b * NQ + qbase + q) * DD + lane] = sum / Tb[q];
    }
}

extern "C" void kernel_launch(void* const* d_in, const int* in_sizes, int n_in,
                              void* d_out, int out_size, void* d_ws, size_t ws_size,
                              hipStream_t stream) {
    const float* Qp = (const float*)d_in[0];
    const float* Kp = (const float*)d_in[1];
    const float* Vp = (const float*)d_in[2];
    const int*   VL = (const int*)d_in[3];
    float* Op = (float*)d_out;

    char* Kh = (char*)d_ws;                                   // 2 MB
    char* Vt = (char*)d_ws + (size_t)NB * NT * TILE_BYTES;    // 2 MB

    dim3 block(256);
    hipLaunchKernelGGL(convert_kv, dim3(2 * NB * NT), block, 0, stream,
                       Kp, Vp, Kh, Vt);
    hipLaunchKernelGGL(attn_fused, dim3(NB * (NQ / 32)), block, 0, stream,
                       Qp, Kh, Vt, VL, Op);
}